// Round 1
// baseline (439.759 us; speedup 1.0000x reference)
//
#include <hip/hip_runtime.h>
#include <math.h>
#include <float.h>

#define IN_DIM   1024
#define OUT_DIM  128
#define MEM_LEN  131072
#define DIST_BLOCKS 2048   // 4 waves/block * 16 rows/wave * 2048 = 131072 rows
#define COPY_BLOCKS 2048

// insert (v,i) into ascending-(v,i) top-3; lexicographic tie-break matches
// jax.lax.top_k stability (lower index wins on equal distance)
__device__ __forceinline__ void ins3(float v, int i,
    float& v0, int& i0, float& v1, int& i1, float& v2, int& i2) {
  if (v < v0 || (v == v0 && i < i0)) {
    v2 = v1; i2 = i1; v1 = v0; i1 = i0; v0 = v; i0 = i;
  } else if (v < v1 || (v == v1 && i < i1)) {
    v2 = v1; i2 = i1; v1 = v; i1 = i;
  } else if (v < v2 || (v == v2 && i < i2)) {
    v2 = v; i2 = i;
  }
}

// K1: normalize + encoder + decoder-MSE + win_loss. Single block, 1024 threads.
__global__ __launch_bounds__(1024) void k1_encode(
    const float* __restrict__ x, const float* __restrict__ mean,
    const float* __restrict__ stdv, const float* __restrict__ W_enc,
    const float* __restrict__ b_enc, const float* __restrict__ W_dec,
    const float* __restrict__ b_dec, const float* __restrict__ win_mean,
    const float* __restrict__ win_std,
    float* __restrict__ ws_enc, float* __restrict__ ws_winloss) {
  __shared__ float s_new[IN_DIM];
  __shared__ float s_part[8][OUT_DIM];
  __shared__ float s_enc[OUT_DIM];
  __shared__ float s_red[16];
  const int t = threadIdx.x;
  const float sd = stdv[t];
  const float nv = (sd == 0.0f) ? 0.0f : (x[t] - mean[t]) / sd;
  s_new[t] = nv;
  __syncthreads();
  // enc partials: o = t&127, p = t>>7; k = p*128+i  (W_enc reads coalesced)
  const int o = t & (OUT_DIM - 1);
  const int p = t >> 7;
  float partial = 0.0f;
  #pragma unroll 8
  for (int i = 0; i < 128; ++i) {
    const int k = p * 128 + i;
    partial += s_new[k] * W_enc[k * OUT_DIM + o];
  }
  s_part[p][o] = partial;
  __syncthreads();
  if (t < OUT_DIM) {
    float sum = b_enc[t];
    #pragma unroll
    for (int pp = 0; pp < 8; ++pp) sum += s_part[pp][t];
    const float e = tanhf(sum);
    s_enc[t] = e;
    ws_enc[t] = e;
  }
  __syncthreads();
  // rec + per-element squared error
  float r = b_dec[t];
  #pragma unroll 8
  for (int k = 0; k < OUT_DIM; ++k) r += s_enc[k] * W_dec[k * IN_DIM + t];
  const float diff = r - nv;
  float sq = diff * diff;
  for (int off = 32; off; off >>= 1) sq += __shfl_xor(sq, off, 64);
  const int lane = t & 63, wid = t >> 6;
  if (lane == 0) s_red[wid] = sq;
  __syncthreads();
  if (t == 0) {
    float tot = 0.0f;
    #pragma unroll
    for (int w = 0; w < 16; ++w) tot += s_red[w];
    const float mse = tot / (float)IN_DIM;
    const float z = (mse - win_mean[0]) / win_std[0];
    const float prob = 0.5f * erfcf(-z * 0.70710678118654752440f); // ndtr
    ws_winloss[0] = (1.0f - prob) * mse;  // SKIP_THRESHOLD == 1
  }
}

// K2: fused L1-distance scan + memory -> out copy. Wave-per-row.
__global__ __launch_bounds__(256) void k2_dist_copy(
    const float* __restrict__ memory, const float* __restrict__ ws_enc,
    float* __restrict__ out_mem, float* __restrict__ topv, int* __restrict__ topi) {
  const int t = threadIdx.x;
  const int lane = t & 63;
  const int wid = t >> 6;                       // 0..3
  const int gw = blockIdx.x * 4 + wid;          // global wave 0..8191
  const float2 e = reinterpret_cast<const float2*>(ws_enc)[lane];
  float v0 = FLT_MAX, v1 = FLT_MAX, v2 = FLT_MAX;
  int i0 = 0x7fffffff, i1 = 0x7fffffff, i2 = 0x7fffffff;
  const int r0 = gw * 16;
  for (int rr = 0; rr < 16; ++rr) {
    const int r = r0 + rr;
    const float2 m = reinterpret_cast<const float2*>(memory)[(size_t)r * 64 + lane];
    // copy row to output (out_mem is only 4B-aligned: scalar stores)
    out_mem[(size_t)r * 128 + 2 * lane]     = m.x;
    out_mem[(size_t)r * 128 + 2 * lane + 1] = m.y;
    float d = fabsf(m.x - e.x) + fabsf(m.y - e.y);
    for (int off = 32; off; off >>= 1) d += __shfl_xor(d, off, 64);
    ins3(d, r, v0, i0, v1, i1, v2, i2);         // replicated across lanes
  }
  __shared__ float sv[4][3];
  __shared__ int   si[4][3];
  if (lane == 0) {
    sv[wid][0] = v0; sv[wid][1] = v1; sv[wid][2] = v2;
    si[wid][0] = i0; si[wid][1] = i1; si[wid][2] = i2;
  }
  __syncthreads();
  if (t == 0) {
    for (int w = 1; w < 4; ++w)
      for (int j = 0; j < 3; ++j)
        ins3(sv[w][j], si[w][j], v0, i0, v1, i1, v2, i2);
    topv[blockIdx.x * 3 + 0] = v0; topi[blockIdx.x * 3 + 0] = i0;
    topv[blockIdx.x * 3 + 1] = v1; topi[blockIdx.x * 3 + 1] = i1;
    topv[blockIdx.x * 3 + 2] = v2; topi[blockIdx.x * 3 + 2] = i2;
  }
}

// mem_data -> out copy. float4 loads (src 16B aligned); dst only 4B aligned.
__global__ __launch_bounds__(256) void k_copy_md(
    const float4* __restrict__ src, float* __restrict__ dst, int n4) {
  int i = blockIdx.x * 256 + threadIdx.x;
  const int stride = COPY_BLOCKS * 256;
  for (; i < n4; i += stride) {
    const float4 v = src[i];
    float* d = dst + (size_t)i * 4;
    d[0] = v.x; d[1] = v.y; d[2] = v.z; d[3] = v.w;
  }
}

// K3: merge 2048*3 candidates, compute final loss + flags.
__global__ __launch_bounds__(1024) void k3_topk(
    const float* __restrict__ topv, const int* __restrict__ topi,
    const float* __restrict__ ws_winloss, float* __restrict__ out_loss,
    int* __restrict__ flags) {
  const int t = threadIdx.x;
  const int n = DIST_BLOCKS * 3;   // 6144
  float v0 = FLT_MAX, v1 = FLT_MAX, v2 = FLT_MAX;
  int i0 = 0x7fffffff, i1 = 0x7fffffff, i2 = 0x7fffffff;
  for (int j = t; j < n; j += 1024) ins3(topv[j], topi[j], v0, i0, v1, i1, v2, i2);
  for (int off = 32; off; off >>= 1) {
    const float ov0 = __shfl_xor(v0, off, 64);
    const float ov1 = __shfl_xor(v1, off, 64);
    const float ov2 = __shfl_xor(v2, off, 64);
    const int oi0 = __shfl_xor(i0, off, 64);
    const int oi1 = __shfl_xor(i1, off, 64);
    const int oi2 = __shfl_xor(i2, off, 64);
    ins3(ov0, oi0, v0, i0, v1, i1, v2, i2);
    ins3(ov1, oi1, v0, i0, v1, i1, v2, i2);
    ins3(ov2, oi2, v0, i0, v1, i1, v2, i2);
  }
  __shared__ float sv[16][3];
  __shared__ int   si[16][3];
  const int lane = t & 63, wid = t >> 6;
  if (lane == 0) {
    sv[wid][0] = v0; sv[wid][1] = v1; sv[wid][2] = v2;
    si[wid][0] = i0; si[wid][1] = i1; si[wid][2] = i2;
  }
  __syncthreads();
  if (t == 0) {
    for (int w = 1; w < 16; ++w)
      for (int j = 0; j < 3; ++j)
        ins3(sv[w][j], si[w][j], v0, i0, v1, i1, v2, i2);
    const float loss_values = (v0 + 0.5f * v1 + 0.25f * v2) / 1.75f;
    const float wl = ws_winloss[0];
    out_loss[0] = wl + loss_values;
    flags[0] = i0;
    flags[1] = (loss_values <= wl) ? 1 : 0;
  }
}

// K4: conditional single-row FIFO update of both output copies.
__global__ __launch_bounds__(1024) void k4_update(
    const int* __restrict__ flags, const float* __restrict__ ws_enc,
    const float* __restrict__ x,
    float* __restrict__ out_mem, float* __restrict__ out_md) {
  if (flags[1] == 0) return;
  const int i0 = flags[0];
  const int t = threadIdx.x;
  if (t < OUT_DIM) out_mem[(size_t)i0 * OUT_DIM + t] = ws_enc[t];
  out_md[(size_t)i0 * IN_DIM + t] = x[t];
}

extern "C" void kernel_launch(void* const* d_in, const int* in_sizes, int n_in,
                              void* d_out, int out_size, void* d_ws, size_t ws_size,
                              hipStream_t stream) {
  const float* x        = (const float*)d_in[0];
  const float* mean     = (const float*)d_in[1];
  const float* stdv     = (const float*)d_in[2];
  const float* memory   = (const float*)d_in[3];
  const float* mem_data = (const float*)d_in[4];
  const float* W_enc    = (const float*)d_in[5];
  const float* b_enc    = (const float*)d_in[6];
  const float* W_dec    = (const float*)d_in[7];
  const float* b_dec    = (const float*)d_in[8];
  const float* win_mean = (const float*)d_in[9];
  const float* win_std  = (const float*)d_in[10];

  float* out      = (float*)d_out;
  float* out_loss = out;
  float* out_mem  = out + 1;
  float* out_md   = out + 1 + (size_t)MEM_LEN * OUT_DIM;

  // workspace layout (floats)
  float* ws        = (float*)d_ws;
  float* ws_enc    = ws;                     // 128
  float* ws_wl     = ws + 128;               // 1 (win_loss)
  float* ws_topv   = ws + 256;               // 6144
  int*   ws_topi   = (int*)(ws + 256 + DIST_BLOCKS * 3);   // 6144
  int*   ws_flags  = (int*)(ws + 256 + 2 * DIST_BLOCKS * 3); // 2

  k1_encode<<<1, 1024, 0, stream>>>(x, mean, stdv, W_enc, b_enc, W_dec, b_dec,
                                    win_mean, win_std, ws_enc, ws_wl);
  k2_dist_copy<<<DIST_BLOCKS, 256, 0, stream>>>(memory, ws_enc, out_mem,
                                                ws_topv, ws_topi);
  k_copy_md<<<COPY_BLOCKS, 256, 0, stream>>>((const float4*)mem_data, out_md,
                                             (int)((size_t)MEM_LEN * IN_DIM / 4));
  k3_topk<<<1, 1024, 0, stream>>>(ws_topv, ws_topi, ws_wl, out_loss, ws_flags);
  k4_update<<<1, 1024, 0, stream>>>(ws_flags, ws_enc, x, out_mem, out_md);
}

// Round 2
// 383.616 us; speedup vs baseline: 1.1464x; 1.1464x over previous
//
#include <hip/hip_runtime.h>
#include <math.h>
#include <float.h>

#define IN_DIM   1024
#define OUT_DIM  128
#define MEM_LEN  131072
#define DIST_BLOCKS 2048   // 4 waves/block * 16 rows/wave * 2048 = 131072 rows
#define COPY_BLOCKS 2048

// insert (v,i) into ascending-(v,i) top-3; lexicographic tie-break matches
// jax.lax.top_k stability (lower index wins on equal distance)
__device__ __forceinline__ void ins3(float v, int i,
    float& v0, int& i0, float& v1, int& i1, float& v2, int& i2) {
  if (v < v0 || (v == v0 && i < i0)) {
    v2 = v1; i2 = i1; v1 = v0; i1 = i0; v0 = v; i0 = i;
  } else if (v < v1 || (v == v1 && i < i1)) {
    v2 = v1; i2 = i1; v1 = v; i1 = i;
  } else if (v < v2 || (v == v2 && i < i2)) {
    v2 = v; i2 = i;
  }
}

// K1: normalize + encoder + decoder-MSE + win_loss. Single block, 1024 threads.
__global__ __launch_bounds__(1024) void k1_encode(
    const float* __restrict__ x, const float* __restrict__ mean,
    const float* __restrict__ stdv, const float* __restrict__ W_enc,
    const float* __restrict__ b_enc, const float* __restrict__ W_dec,
    const float* __restrict__ b_dec, const float* __restrict__ win_mean,
    const float* __restrict__ win_std,
    float* __restrict__ ws_enc, float* __restrict__ ws_winloss) {
  __shared__ float s_new[IN_DIM];
  __shared__ float s_part[8][OUT_DIM];
  __shared__ float s_enc[OUT_DIM];
  __shared__ float s_red[16];
  const int t = threadIdx.x;
  const float sd = stdv[t];
  const float nv = (sd == 0.0f) ? 0.0f : (x[t] - mean[t]) / sd;
  s_new[t] = nv;
  __syncthreads();
  // enc partials: o = t&127, p = t>>7; k = p*128+i  (W_enc reads coalesced)
  const int o = t & (OUT_DIM - 1);
  const int p = t >> 7;
  float partial = 0.0f;
  #pragma unroll 8
  for (int i = 0; i < 128; ++i) {
    const int k = p * 128 + i;
    partial += s_new[k] * W_enc[k * OUT_DIM + o];
  }
  s_part[p][o] = partial;
  __syncthreads();
  if (t < OUT_DIM) {
    float sum = b_enc[t];
    #pragma unroll
    for (int pp = 0; pp < 8; ++pp) sum += s_part[pp][t];
    const float e = tanhf(sum);
    s_enc[t] = e;
    ws_enc[t] = e;
  }
  __syncthreads();
  // rec + per-element squared error
  float r = b_dec[t];
  #pragma unroll 8
  for (int k = 0; k < OUT_DIM; ++k) r += s_enc[k] * W_dec[k * IN_DIM + t];
  const float diff = r - nv;
  float sq = diff * diff;
  for (int off = 32; off; off >>= 1) sq += __shfl_xor(sq, off, 64);
  const int lane = t & 63, wid = t >> 6;
  if (lane == 0) s_red[wid] = sq;
  __syncthreads();
  if (t == 0) {
    float tot = 0.0f;
    #pragma unroll
    for (int w = 0; w < 16; ++w) tot += s_red[w];
    const float mse = tot / (float)IN_DIM;
    const float z = (mse - win_mean[0]) / win_std[0];
    const float prob = 0.5f * erfcf(-z * 0.70710678118654752440f); // ndtr
    ws_winloss[0] = (1.0f - prob) * mse;  // SKIP_THRESHOLD == 1
  }
}

// K2: L1-distance scan only (no copy). Wave-per-row, 16 rows/wave.
__global__ __launch_bounds__(256) void k2_dist(
    const float* __restrict__ memory, const float* __restrict__ ws_enc,
    float* __restrict__ topv, int* __restrict__ topi) {
  const int t = threadIdx.x;
  const int lane = t & 63;
  const int wid = t >> 6;                       // 0..3
  const int gw = blockIdx.x * 4 + wid;          // global wave 0..8191
  const float2 e = reinterpret_cast<const float2*>(ws_enc)[lane];
  float v0 = FLT_MAX, v1 = FLT_MAX, v2 = FLT_MAX;
  int i0 = 0x7fffffff, i1 = 0x7fffffff, i2 = 0x7fffffff;
  const int r0 = gw * 16;
  for (int rr = 0; rr < 16; ++rr) {
    const int r = r0 + rr;
    const float2 m = reinterpret_cast<const float2*>(memory)[(size_t)r * 64 + lane];
    float d = fabsf(m.x - e.x) + fabsf(m.y - e.y);
    for (int off = 32; off; off >>= 1) d += __shfl_xor(d, off, 64);
    ins3(d, r, v0, i0, v1, i1, v2, i2);         // replicated across lanes
  }
  __shared__ float sv[4][3];
  __shared__ int   si[4][3];
  if (lane == 0) {
    sv[wid][0] = v0; sv[wid][1] = v1; sv[wid][2] = v2;
    si[wid][0] = i0; si[wid][1] = i1; si[wid][2] = i2;
  }
  __syncthreads();
  if (t == 0) {
    for (int w = 1; w < 4; ++w)
      for (int j = 0; j < 3; ++j)
        ins3(sv[w][j], si[w][j], v0, i0, v1, i1, v2, i2);
    topv[blockIdx.x * 3 + 0] = v0; topi[blockIdx.x * 3 + 0] = i0;
    topv[blockIdx.x * 3 + 1] = v1; topi[blockIdx.x * 3 + 1] = i1;
    topv[blockIdx.x * 3 + 2] = v2; topi[blockIdx.x * 3 + 2] = i2;
  }
}

// Realigned copy: src is 16B-aligned, dst is 4B-aligned with dst%16B == 4.
// Thread k stores the 16B-aligned chunk dst[3+4k .. 6+4k] built from
// src4[k].w (scalar dword, same cacheline as neighbor's x4 -> L2 hit) and
// src4[k+1].xyz. Head (3 floats) + tail scalars by thread 0.
__global__ __launch_bounds__(256) void copy_realign4(
    const float* __restrict__ src, float* __restrict__ dst, long long n) {
  const long long K = (n - 3) >> 2;
  long long k = (long long)blockIdx.x * 256 + threadIdx.x;
  const long long stride = (long long)gridDim.x * 256;
  const float4* s4 = reinterpret_cast<const float4*>(src);
  for (; k < K; k += stride) {
    const float4 b = s4[k + 1];
    const float aw = src[4 * k + 3];
    const float4 v = make_float4(aw, b.x, b.y, b.z);
    *reinterpret_cast<float4*>(dst + 3 + 4 * k) = v;
  }
  if (blockIdx.x == 0 && threadIdx.x == 0) {
    dst[0] = src[0]; dst[1] = src[1]; dst[2] = src[2];
    for (long long e = 3 + 4 * K; e < n; ++e) dst[e] = src[e];
  }
}

// K3+K4: merge 2048*3 candidates, final loss, conditional FIFO row update.
__global__ __launch_bounds__(1024) void k3_topk_update(
    const float* __restrict__ topv, const int* __restrict__ topi,
    const float* __restrict__ ws_winloss, const float* __restrict__ ws_enc,
    const float* __restrict__ x, float* __restrict__ out_loss,
    float* __restrict__ out_mem, float* __restrict__ out_md) {
  const int t = threadIdx.x;
  const int n = DIST_BLOCKS * 3;   // 6144
  float v0 = FLT_MAX, v1 = FLT_MAX, v2 = FLT_MAX;
  int i0 = 0x7fffffff, i1 = 0x7fffffff, i2 = 0x7fffffff;
  for (int j = t; j < n; j += 1024) ins3(topv[j], topi[j], v0, i0, v1, i1, v2, i2);
  for (int off = 32; off; off >>= 1) {
    const float ov0 = __shfl_xor(v0, off, 64);
    const float ov1 = __shfl_xor(v1, off, 64);
    const float ov2 = __shfl_xor(v2, off, 64);
    const int oi0 = __shfl_xor(i0, off, 64);
    const int oi1 = __shfl_xor(i1, off, 64);
    const int oi2 = __shfl_xor(i2, off, 64);
    ins3(ov0, oi0, v0, i0, v1, i1, v2, i2);
    ins3(ov1, oi1, v0, i0, v1, i1, v2, i2);
    ins3(ov2, oi2, v0, i0, v1, i1, v2, i2);
  }
  __shared__ float sv[16][3];
  __shared__ int   si[16][3];
  __shared__ int s_i0, s_cond;
  const int lane = t & 63, wid = t >> 6;
  if (lane == 0) {
    sv[wid][0] = v0; sv[wid][1] = v1; sv[wid][2] = v2;
    si[wid][0] = i0; si[wid][1] = i1; si[wid][2] = i2;
  }
  __syncthreads();
  if (t == 0) {
    for (int w = 1; w < 16; ++w)
      for (int j = 0; j < 3; ++j)
        ins3(sv[w][j], si[w][j], v0, i0, v1, i1, v2, i2);
    const float loss_values = (v0 + 0.5f * v1 + 0.25f * v2) / 1.75f;
    const float wl = ws_winloss[0];
    out_loss[0] = wl + loss_values;
    s_i0 = i0;
    s_cond = (loss_values <= wl) ? 1 : 0;
  }
  __syncthreads();
  if (s_cond) {
    if (t < OUT_DIM) out_mem[(size_t)s_i0 * OUT_DIM + t] = ws_enc[t];
    out_md[(size_t)s_i0 * IN_DIM + t] = x[t];
  }
}

extern "C" void kernel_launch(void* const* d_in, const int* in_sizes, int n_in,
                              void* d_out, int out_size, void* d_ws, size_t ws_size,
                              hipStream_t stream) {
  const float* x        = (const float*)d_in[0];
  const float* mean     = (const float*)d_in[1];
  const float* stdv     = (const float*)d_in[2];
  const float* memory   = (const float*)d_in[3];
  const float* mem_data = (const float*)d_in[4];
  const float* W_enc    = (const float*)d_in[5];
  const float* b_enc    = (const float*)d_in[6];
  const float* W_dec    = (const float*)d_in[7];
  const float* b_dec    = (const float*)d_in[8];
  const float* win_mean = (const float*)d_in[9];
  const float* win_std  = (const float*)d_in[10];

  float* out      = (float*)d_out;
  float* out_loss = out;
  float* out_mem  = out + 1;
  float* out_md   = out + 1 + (size_t)MEM_LEN * OUT_DIM;

  // workspace layout (floats)
  float* ws        = (float*)d_ws;
  float* ws_enc    = ws;                     // 128
  float* ws_wl     = ws + 128;               // 1 (win_loss)
  float* ws_topv   = ws + 256;               // 6144
  int*   ws_topi   = (int*)(ws + 256 + DIST_BLOCKS * 3);   // 6144

  k1_encode<<<1, 1024, 0, stream>>>(x, mean, stdv, W_enc, b_enc, W_dec, b_dec,
                                    win_mean, win_std, ws_enc, ws_wl);
  k2_dist<<<DIST_BLOCKS, 256, 0, stream>>>(memory, ws_enc, ws_topv, ws_topi);
  // memory was just read by k2 -> resident in L3; re-read is ~free.
  copy_realign4<<<COPY_BLOCKS, 256, 0, stream>>>(memory, out_mem,
                                                 (long long)MEM_LEN * OUT_DIM);
  copy_realign4<<<COPY_BLOCKS, 256, 0, stream>>>(mem_data, out_md,
                                                 (long long)MEM_LEN * IN_DIM);
  k3_topk_update<<<1, 1024, 0, stream>>>(ws_topv, ws_topi, ws_wl, ws_enc, x,
                                         out_loss, out_mem, out_md);
}

// Round 3
// 356.987 us; speedup vs baseline: 1.2319x; 1.0746x over previous
//
#include <hip/hip_runtime.h>
#include <math.h>
#include <float.h>

#define IN_DIM   1024
#define OUT_DIM  128
#define MEM_LEN  131072
#define DIST_BLOCKS 2048    // 4 waves/block * 16 rows/wave * 2048 = 131072 rows
#define COPY_BLOCKS 8192

#define NA_FLOATS  ((long long)MEM_LEN * OUT_DIM)            // 16,777,216
#define NB_FLOATS  ((long long)MEM_LEN * IN_DIM)             // 134,217,728
#define N_TOTAL    (NA_FLOATS + NB_FLOATS)                   // 150,994,944
#define NA_CHUNKS  (NA_FLOATS / 4)                           // 4,194,304
#define CMAX       ((N_TOTAL - 4) / 4)                       // 37,748,735 (last full dst chunk)

// insert (v,i) into ascending-(v,i) top-3; lexicographic tie-break matches
// jax.lax.top_k stability (lower index wins on equal distance)
__device__ __forceinline__ void ins3(float v, int i,
    float& v0, int& i0, float& v1, int& i1, float& v2, int& i2) {
  if (v < v0 || (v == v0 && i < i0)) {
    v2 = v1; i2 = i1; v1 = v0; i1 = i0; v0 = v; i0 = i;
  } else if (v < v1 || (v == v1 && i < i1)) {
    v2 = v1; i2 = i1; v1 = v; i1 = i;
  } else if (v < v2 || (v == v2 && i < i2)) {
    v2 = v; i2 = i;
  }
}

// K1: normalize + encoder + decoder-MSE + win_loss. Single block, 1024 threads.
__global__ __launch_bounds__(1024) void k1_encode(
    const float* __restrict__ x, const float* __restrict__ mean,
    const float* __restrict__ stdv, const float* __restrict__ W_enc,
    const float* __restrict__ b_enc, const float* __restrict__ W_dec,
    const float* __restrict__ b_dec, const float* __restrict__ win_mean,
    const float* __restrict__ win_std,
    float* __restrict__ ws_enc, float* __restrict__ ws_winloss) {
  __shared__ float s_new[IN_DIM];
  __shared__ float s_part[8][OUT_DIM];
  __shared__ float s_enc[OUT_DIM];
  __shared__ float s_red[16];
  const int t = threadIdx.x;
  const float sd = stdv[t];
  const float nv = (sd == 0.0f) ? 0.0f : (x[t] - mean[t]) / sd;
  s_new[t] = nv;
  __syncthreads();
  const int o = t & (OUT_DIM - 1);
  const int p = t >> 7;
  float partial = 0.0f;
  #pragma unroll 8
  for (int i = 0; i < 128; ++i) {
    const int k = p * 128 + i;
    partial += s_new[k] * W_enc[k * OUT_DIM + o];
  }
  s_part[p][o] = partial;
  __syncthreads();
  if (t < OUT_DIM) {
    float sum = b_enc[t];
    #pragma unroll
    for (int pp = 0; pp < 8; ++pp) sum += s_part[pp][t];
    const float e = tanhf(sum);
    s_enc[t] = e;
    ws_enc[t] = e;
  }
  __syncthreads();
  float r = b_dec[t];
  #pragma unroll 8
  for (int k = 0; k < OUT_DIM; ++k) r += s_enc[k] * W_dec[k * IN_DIM + t];
  const float diff = r - nv;
  float sq = diff * diff;
  for (int off = 32; off; off >>= 1) sq += __shfl_xor(sq, off, 64);
  const int lane = t & 63, wid = t >> 6;
  if (lane == 0) s_red[wid] = sq;
  __syncthreads();
  if (t == 0) {
    float tot = 0.0f;
    #pragma unroll
    for (int w = 0; w < 16; ++w) tot += s_red[w];
    const float mse = tot / (float)IN_DIM;
    const float z = (mse - win_mean[0]) / win_std[0];
    const float prob = 0.5f * erfcf(-z * 0.70710678118654752440f); // ndtr
    ws_winloss[0] = (1.0f - prob) * mse;  // SKIP_THRESHOLD == 1
  }
}

// K2: L1-distance scan only. Wave-per-row, 16 rows/wave.
__global__ __launch_bounds__(256) void k2_dist(
    const float* __restrict__ memory, const float* __restrict__ ws_enc,
    float* __restrict__ topv, int* __restrict__ topi) {
  const int t = threadIdx.x;
  const int lane = t & 63;
  const int wid = t >> 6;
  const int gw = blockIdx.x * 4 + wid;
  const float2 e = reinterpret_cast<const float2*>(ws_enc)[lane];
  float v0 = FLT_MAX, v1 = FLT_MAX, v2 = FLT_MAX;
  int i0 = 0x7fffffff, i1 = 0x7fffffff, i2 = 0x7fffffff;
  const int r0 = gw * 16;
  for (int rr = 0; rr < 16; ++rr) {
    const int r = r0 + rr;
    const float2 m = reinterpret_cast<const float2*>(memory)[(size_t)r * 64 + lane];
    float d = fabsf(m.x - e.x) + fabsf(m.y - e.y);
    for (int off = 32; off; off >>= 1) d += __shfl_xor(d, off, 64);
    ins3(d, r, v0, i0, v1, i1, v2, i2);
  }
  __shared__ float sv[4][3];
  __shared__ int   si[4][3];
  if (lane == 0) {
    sv[wid][0] = v0; sv[wid][1] = v1; sv[wid][2] = v2;
    si[wid][0] = i0; si[wid][1] = i1; si[wid][2] = i2;
  }
  __syncthreads();
  if (t == 0) {
    for (int w = 1; w < 4; ++w)
      for (int j = 0; j < 3; ++j)
        ins3(sv[w][j], si[w][j], v0, i0, v1, i1, v2, i2);
    topv[blockIdx.x * 3 + 0] = v0; topi[blockIdx.x * 3 + 0] = i0;
    topv[blockIdx.x * 3 + 1] = v1; topi[blockIdx.x * 3 + 1] = i1;
    topv[blockIdx.x * 3 + 2] = v2; topi[blockIdx.x * 3 + 2] = i2;
  }
}

// Unified realigned copy of out[1..N_TOTAL] <- {memory, mem_data}.
// dst chunk c (16B-aligned, c in [1, CMAX]) = out[4c..4c+3]
//   = { V[c-1].w, V[c].x, V[c].y, V[c].z }
// where V[c] = c < NA_CHUNKS ? memory4[c] : mem_data4[c - NA_CHUNKS]
// (NA_FLOATS % 4 == 0 so V never straddles the region boundary).
// Each wave takes 64 consecutive chunks: V[c-1].w comes from lane-1 via
// shfl_up; lane 0 scalar-loads the one boundary dword (L2-hit).
__global__ __launch_bounds__(256) void copy_all(
    const float4* __restrict__ mem4, const float4* __restrict__ md4,
    float* __restrict__ out) {
  const int lane = threadIdx.x & 63;
  const int wid  = threadIdx.x >> 6;
  const long long wstride = (long long)gridDim.x * 4;
  const long long ngroups = (CMAX + 63) / 64;   // groups of 64 chunks, from c=1
  const float* memf = reinterpret_cast<const float*>(mem4);
  const float* mdf  = reinterpret_cast<const float*>(md4);
  for (long long g = (long long)blockIdx.x * 4 + wid; g < ngroups; g += wstride) {
    const long long c = 1 + g * 64 + lane;
    const bool valid = (c <= CMAX);
    float4 v = make_float4(0.f, 0.f, 0.f, 0.f);
    if (valid) v = (c < NA_CHUNKS) ? mem4[c] : md4[c - NA_CHUNKS];
    float aw = __shfl_up(v.w, 1, 64);
    if (lane == 0) {
      const long long s = 4 * c - 1;   // = 256g + 3
      aw = (s < NA_FLOATS) ? memf[s] : mdf[s - NA_FLOATS];
    }
    if (valid) {
      const float4 o = make_float4(aw, v.x, v.y, v.z);
      *reinterpret_cast<float4*>(out + 4 * c) = o;
    }
  }
  if (blockIdx.x == 0 && threadIdx.x == 0) {
    out[1] = memf[0]; out[2] = memf[1]; out[3] = memf[2];
    out[N_TOTAL] = mdf[NB_FLOATS - 1];
  }
}

// K3+K4: merge candidates, final loss, conditional FIFO row update.
__global__ __launch_bounds__(1024) void k3_topk_update(
    const float* __restrict__ topv, const int* __restrict__ topi,
    const float* __restrict__ ws_winloss, const float* __restrict__ ws_enc,
    const float* __restrict__ x, float* __restrict__ out_loss,
    float* __restrict__ out_mem, float* __restrict__ out_md) {
  const int t = threadIdx.x;
  const int n = DIST_BLOCKS * 3;
  float v0 = FLT_MAX, v1 = FLT_MAX, v2 = FLT_MAX;
  int i0 = 0x7fffffff, i1 = 0x7fffffff, i2 = 0x7fffffff;
  for (int j = t; j < n; j += 1024) ins3(topv[j], topi[j], v0, i0, v1, i1, v2, i2);
  for (int off = 32; off; off >>= 1) {
    const float ov0 = __shfl_xor(v0, off, 64);
    const float ov1 = __shfl_xor(v1, off, 64);
    const float ov2 = __shfl_xor(v2, off, 64);
    const int oi0 = __shfl_xor(i0, off, 64);
    const int oi1 = __shfl_xor(i1, off, 64);
    const int oi2 = __shfl_xor(i2, off, 64);
    ins3(ov0, oi0, v0, i0, v1, i1, v2, i2);
    ins3(ov1, oi1, v0, i0, v1, i1, v2, i2);
    ins3(ov2, oi2, v0, i0, v1, i1, v2, i2);
  }
  __shared__ float sv[16][3];
  __shared__ int   si[16][3];
  __shared__ int s_i0, s_cond;
  const int lane = t & 63, wid = t >> 6;
  if (lane == 0) {
    sv[wid][0] = v0; sv[wid][1] = v1; sv[wid][2] = v2;
    si[wid][0] = i0; si[wid][1] = i1; si[wid][2] = i2;
  }
  __syncthreads();
  if (t == 0) {
    for (int w = 1; w < 16; ++w)
      for (int j = 0; j < 3; ++j)
        ins3(sv[w][j], si[w][j], v0, i0, v1, i1, v2, i2);
    const float loss_values = (v0 + 0.5f * v1 + 0.25f * v2) / 1.75f;
    const float wl = ws_winloss[0];
    out_loss[0] = wl + loss_values;
    s_i0 = i0;
    s_cond = (loss_values <= wl) ? 1 : 0;
  }
  __syncthreads();
  if (s_cond) {
    if (t < OUT_DIM) out_mem[(size_t)s_i0 * OUT_DIM + t] = ws_enc[t];
    out_md[(size_t)s_i0 * IN_DIM + t] = x[t];
  }
}

extern "C" void kernel_launch(void* const* d_in, const int* in_sizes, int n_in,
                              void* d_out, int out_size, void* d_ws, size_t ws_size,
                              hipStream_t stream) {
  const float* x        = (const float*)d_in[0];
  const float* mean     = (const float*)d_in[1];
  const float* stdv     = (const float*)d_in[2];
  const float* memory   = (const float*)d_in[3];
  const float* mem_data = (const float*)d_in[4];
  const float* W_enc    = (const float*)d_in[5];
  const float* b_enc    = (const float*)d_in[6];
  const float* W_dec    = (const float*)d_in[7];
  const float* b_dec    = (const float*)d_in[8];
  const float* win_mean = (const float*)d_in[9];
  const float* win_std  = (const float*)d_in[10];

  float* out      = (float*)d_out;
  float* out_loss = out;
  float* out_mem  = out + 1;
  float* out_md   = out + 1 + (size_t)MEM_LEN * OUT_DIM;

  float* ws        = (float*)d_ws;
  float* ws_enc    = ws;                     // 128
  float* ws_wl     = ws + 128;               // 1 (win_loss)
  float* ws_topv   = ws + 256;               // 6144
  int*   ws_topi   = (int*)(ws + 256 + DIST_BLOCKS * 3);   // 6144

  k1_encode<<<1, 1024, 0, stream>>>(x, mean, stdv, W_enc, b_enc, W_dec, b_dec,
                                    win_mean, win_std, ws_enc, ws_wl);
  k2_dist<<<DIST_BLOCKS, 256, 0, stream>>>(memory, ws_enc, ws_topv, ws_topi);
  copy_all<<<COPY_BLOCKS, 256, 0, stream>>>((const float4*)memory,
                                            (const float4*)mem_data, out);
  k3_topk_update<<<1, 1024, 0, stream>>>(ws_topv, ws_topi, ws_wl, ws_enc, x,
                                         out_loss, out_mem, out_md);
}